// Round 17
// baseline (111.893 us; speedup 1.0000x reference)
//
#include <hip/hip_runtime.h>
#include <hip/hip_bf16.h>
#include <math.h>

#define N_B 2
#define C_CH 256
#define HW_SZ 4096
#define CL_CH 16

typedef __bf16 bf16x8 __attribute__((ext_vector_type(8)));
typedef float f32x4 __attribute__((ext_vector_type(4)));
typedef float f32x16 __attribute__((ext_vector_type(16)));

__device__ __forceinline__ unsigned short f2bf(float x){
  __hip_bfloat16 b = __float2bfloat16(x);   // RTNE
  return *reinterpret_cast<unsigned short*>(&b);
}
__device__ __forceinline__ float bf2f(unsigned short u){
  unsigned int w = ((unsigned int)u) << 16;
  return *reinterpret_cast<float*>(&w);
}
// packed f32x2 -> bf16x2 (single v_cvt_pk_bf16_f32)
__device__ __forceinline__ unsigned int cvtpk(float a, float b){
  unsigned int r;
  asm("v_cvt_pk_bf16_f32 %0, %1, %2" : "=v"(r) : "v"(a), "v"(b));
  return r;
}
// tanh = 1 - 2*rcp(1+e^{2x}); NaN-safe at +-inf; rcp err ~1e-7 (<< bf16 ulp)
__device__ __forceinline__ float tanh_fast(float x){
  float e = __expf(2.0f * x);
  return fmaf(-2.0f, __builtin_amdgcn_rcpf(1.0f + e), 1.0f);
}
// async global->LDS, 16B per lane; dst must be wave-uniform base (+lane*16 implicit)
__device__ __forceinline__ void gload16(const void* gsrc, void* lds_dst){
  __builtin_amdgcn_global_load_lds(
      (const __attribute__((address_space(1))) unsigned int*)gsrc,
      (__attribute__((address_space(3))) unsigned int*)lds_dst, 16, 0, 0);
}

// ---------- Stage-1 conv (C->1)
__global__ void k_conv1(const float* __restrict__ f1, const float* __restrict__ f2,
                        const float* __restrict__ w1, const float* __restrict__ w2,
                        const float* __restrict__ b1, const float* __restrict__ b2,
                        float* __restrict__ cv){
  const int i = blockIdx.z, n = blockIdx.y, t = threadIdx.x;
  const int ql = t & 63, cg = t >> 6;
  const int q = blockIdx.x * 64 + ql;
  const float* f = (i ? f2 : f1) + n * C_CH * HW_SZ;
  const float* w = i ? w2 : w1;
  __shared__ float ws[C_CH];
  __shared__ float red[4][72];
  ws[t] = w[t];
  __syncthreads();
  float acc = 0.f;
  #pragma unroll 8
  for (int c = cg * 64; c < cg * 64 + 64; ++c)
    acc += f[c * HW_SZ + q] * ws[c];
  red[cg][ql] = acc;
  __syncthreads();
  if (t < 64){
    float s = red[0][t] + red[1][t] + red[2][t] + red[3][t] + (i ? b2[0] : b1[0]);
    cv[(i * 2 + n) * HW_SZ + blockIdx.x * 64 + t] = s;
  }
}

// ---------- fs_i = bf16(pr_i * f_i) ; clT_i[q][0..15] = bf16(pw_i @ (pr*f) + pb_i)
// pr computed INLINE from cv (softmax folded in).
__global__ void k_scale_cl(const float* __restrict__ f1, const float* __restrict__ f2,
                           const float* __restrict__ cv,
                           const float* __restrict__ pw1, const float* __restrict__ pw2,
                           const float* __restrict__ pb1, const float* __restrict__ pb2,
                           unsigned short* __restrict__ fs1, unsigned short* __restrict__ fs2,
                           unsigned short* __restrict__ clT1, unsigned short* __restrict__ clT2){
  const int i = blockIdx.z, n = blockIdx.y, t = threadIdx.x;
  const int ql = t & 63, cg = t >> 6;
  const int q = blockIdx.x * 64 + ql;
  const float* f = (i ? f2 : f1) + n * C_CH * HW_SZ;
  unsigned short* fs = (i ? fs2 : fs1) + n * C_CH * HW_SZ;
  unsigned short* clT = (i ? clT2 : clT1) + n * 32 * HW_SZ;
  const float* pw = i ? pw2 : pw1;
  const float* pb = i ? pb2 : pb1;
  const float* cvrow = cv + (i * 2 + n) * HW_SZ;
  __shared__ float wls[CL_CH * C_CH];
  __shared__ float red[4][CL_CH][66];
  __shared__ float smr[256];
  #pragma unroll
  for (int j = 0; j < 16; j++) wls[j * 256 + t] = pw[j * 256 + t];
  // inline softmax over the 4096-row
  float sv[16];
  float m = -1e30f;
  #pragma unroll
  for (int j = 0; j < 16; j++){ sv[j] = cvrow[j * 256 + t]; m = fmaxf(m, sv[j]); }
  smr[t] = m; __syncthreads();
  for (int s = 128; s > 0; s >>= 1){ if (t < s) smr[t] = fmaxf(smr[t], smr[t + s]); __syncthreads(); }
  m = smr[0]; __syncthreads();
  float sum = 0.f;
  #pragma unroll
  for (int j = 0; j < 16; j++) sum += __expf(sv[j] - m);
  smr[t] = sum; __syncthreads();
  for (int s = 128; s > 0; s >>= 1){ if (t < s) smr[t] += smr[t + s]; __syncthreads(); }
  const float p = __expf(cvrow[q] - m) * (1.0f / smr[0]);

  float acc[16];
  #pragma unroll
  for (int k = 0; k < 16; k++) acc[k] = 0.f;
  for (int c = cg * 64; c < cg * 64 + 64; ++c){
    float vv = f[c * HW_SZ + q] * p;
    fs[c * HW_SZ + q] = f2bf(vv);
    #pragma unroll
    for (int k = 0; k < 16; k++) acc[k] += wls[k * 256 + c] * vv;
  }
  #pragma unroll
  for (int k = 0; k < 16; k++) red[cg][k][ql] = acc[k];
  __syncthreads();
  #pragma unroll
  for (int j = 0; j < 4; j++){
    int e = j * 256 + t; int k = e >> 6, qq = e & 63;
    float s = red[0][k][qq] + red[1][k][qq] + red[2][k][qq] + red[3][k][qq] + pb[k];
    clT[(blockIdx.x * 64 + qq) * 32 + k] = f2bf(s);
  }
  // zero the k in [16,32) pad
  if (t < 128){
    uint4 zv = {0u, 0u, 0u, 0u};
    int qq = t >> 1, half = t & 1;
    *reinterpret_cast<uint4*>(&clT[(blockIdx.x * 64 + qq) * 32 + 16 + half * 8]) = zv;
  }
}

// ---------- fused hat GEMM via MFMA. C=256 x Q=128 tile, split-K over p-halves.
// PHASED schedule (T3/T4/T5 port): each body = 2 aligned phases, each
// {8 ds_read || stage-issue || dgen-half -> lgkmcnt(0)[+vmcnt(1) in P1] ->
// s_barrier -> setprio(1) 8xMFMA setprio(0) -> s_barrier}. All 4 stage-DMAs
// issue in P0; P1's vmcnt(1) (only vnew newer) retires them with ~1 phase of
// cover; barrier globalizes -> next body's ds_reads race-free. Double buffer:
// all reads complete before the two end-of-phase barriers preceding overwrite.
__global__ __launch_bounds__(512, 2) void k_hat(
    const unsigned short* __restrict__ fs1, const unsigned short* __restrict__ fs2,
    const unsigned short* __restrict__ clT1, const unsigned short* __restrict__ clT2,
    float* __restrict__ hat1, float* __restrict__ hat2,
    float* __restrict__ pt1, float* __restrict__ pt2){
  const int t = threadIdx.x;
  const int bid = blockIdx.x;
  const int xcd = bid & 7, slot = bid >> 3;  // slot 0..31
  const int z = xcd >> 1;                    // 0..3 -> (n,i); 2 XCDs per (n,i)
  const int n = z & 1, i = z >> 1;
  const int x = slot * 2 + (xcd & 1);        // 0..63
  const int qt = x >> 1, ph = x & 1;         // 32 q-tiles(128) x 2 p-halves
  const int q0 = qt * 128;
  const int pbase = ph * 2048;

  const unsigned short* fs = (i ? fs2 : fs1) + n * C_CH * HW_SZ;
  const unsigned short* uT = (i ? clT1 : clT2) + n * 32 * HW_SZ;  // q-side [HW][32]
  const unsigned short* vT = (i ? clT2 : clT1) + n * 32 * HW_SZ;  // p-side [HW][32]
  float* out = (ph ? (i ? pt2 : pt1) : (i ? hat2 : hat1)) + n * C_CH * HW_SZ;

  __shared__ __align__(16) unsigned short fsA[2][C_CH * 64];  // 32KB each: [c][p swz]
  __shared__ __align__(16) unsigned short aT[2][128 * 64];    // 16KB each: [q][p swz]

  const int wv = t >> 6, l = t & 63;
  const int g4 = l >> 4, lr16 = l & 15;      // d-gen (16x16)
  const int g2 = l >> 5, lr32 = l & 31;      // main (32x32)

  const int pfw = wv & 3;                    // dgen p-frag
  const int qh  = wv >> 2;                   // dgen q-half (4 q-frags each)
  const int cblk = wv & 3, qblk = wv >> 2;   // mmain: c [cblk*64,+64), q [qblk*64,+64)

  // ---- one-time u fragments (k-pad zeroed at source): 4 q-frags per wave
  bf16x8 ub[4];
  #pragma unroll
  for (int j = 0; j < 4; ++j)
    ub[j] = *reinterpret_cast<const bf16x8*>(&uT[(q0 + qh * 64 + j * 16 + lr16) * 32 + g4 * 8]);

  f32x16 acc00, acc01, acc10, acc11;         // [cf][qf]
  #pragma unroll
  for (int r = 0; r < 16; ++r){ acc00[r] = 0.f; acc01[r] = 0.f; acc10[r] = 0.f; acc11[r] = 0.f; }
  const f32x4 zz = {0.f, 0.f, 0.f, 0.f};

  // ---- per-thread byte offsets (computed once); slot swizzle:
  // slot(row, u) = u ^ (row&7) ^ ((row>>3)&1)<<2 ^ ((row>>4)&1)<<1
  int fs_src[4];
  #pragma unroll
  for (int it = 0; it < 4; ++it){
    int d = it * 512 + t; int c = d >> 3, sl = d & 7;
    int u = sl ^ (c & 7) ^ (((c >> 3) & 1) << 2) ^ (((c >> 4) & 1) << 1);
    fs_src[it] = c * (HW_SZ * 2) + u * 16;
  }
  const int vgo = (pfw * 16 + lr16) * 64 + g4 * 16;  // per-lane byte off within v chunk
  unsigned atw0;
  {
    int qd = qh * 64 + lr16;   // bit4 of qd = 0; j-walk adds j*16 (bit4 = j&1)
    int sw = (pfw * 2 + (g4 >> 1)) ^ (qd & 7) ^ (((qd >> 3) & 1) << 2);
    atw0 = qd * 128 + sw * 16 + (g4 & 1) * 8;
  }
  unsigned afo[2], bqo[2];
  #pragma unroll
  for (int cf = 0; cf < 2; ++cf){
    int crow = cblk * 64 + cf * 32 + lr32;
    afo[cf] = crow * 128 +
      ((g2 ^ (crow & 7) ^ (((crow >> 3) & 1) << 2) ^ (((crow >> 4) & 1) << 1)) << 4);
  }
  #pragma unroll
  for (int qf = 0; qf < 2; ++qf){
    int qrow = qblk * 64 + qf * 32 + lr32;
    bqo[qf] = qrow * 128 +
      ((g2 ^ (qrow & 7) ^ (((qrow >> 3) & 1) << 2) ^ (((qrow >> 4) & 1) << 1)) << 4);
  }

  auto stage_fs = [&](char* dstbase, const char* src){
    #pragma unroll
    for (int it = 0; it < 4; ++it)
      gload16(src + fs_src[it], dstbase + (it * 512 + wv * 64) * 16);
  };
  // dgen half: frags j0, j0+1 (j0 literal 0 or 2)
  auto dgen2 = [&](uint4 vr, char* atB, int j0){
    bf16x8 av = *reinterpret_cast<bf16x8*>(&vr);
    #pragma unroll
    for (int j = 0; j < 2; ++j){
      int jj = j0 + j;
      f32x4 d = __builtin_amdgcn_mfma_f32_16x16x32_bf16(av, ub[jj], zz, 0, 0, 0);
      uint2 pk;
      pk.x = cvtpk(tanh_fast(d[0]), tanh_fast(d[1]));
      pk.y = cvtpk(tanh_fast(d[2]), tanh_fast(d[3]));
      unsigned off = (atw0 + (unsigned)(jj * 2048)) ^ ((unsigned)(jj & 1) << 5);
      *reinterpret_cast<uint2*>(atB + off) = pk;
    }
  };

  // advancing pointers (hot loop: one add each)
  const char* fpp = (const char*)fs + pbase * 2;       // fs chunk base, +128B/chunk
  const char* vp  = (const char*)vT + pbase * 64 + vgo;// per-lane v ptr, +4096B/chunk

  char *fRd = (char*)&fsA[0][0], *fWr = (char*)&fsA[1][0];
  char *aRd = (char*)&aT[0][0],  *aWr = (char*)&aT[1][0];

  // ---- prologue: DMA chunk0 FIRST, then vloads; dgen(v0) waits v0 =>
  // chunk-0 DMA retired per-wave; lgkmcnt+barrier globalizes.
  stage_fs(fRd, fpp); fpp += 128;
  uint4 vb;
  {
    uint4 va = *reinterpret_cast<const uint4*>(vp);        // v chunk 0
    vb = *reinterpret_cast<const uint4*>(vp + 4096);       // v chunk 1
    vp += 8192;
    dgen2(va, aRd, 0);
    dgen2(va, aRd, 2);
  }
  asm volatile("s_waitcnt lgkmcnt(0)" ::: "memory");
  __builtin_amdgcn_sched_barrier(0);
  __builtin_amdgcn_s_barrier();
  __builtin_amdgcn_sched_barrier(0);

  // ---- main loop: 32 chunks, 2 phases each, 4 drain-free barriers/body.
  #pragma unroll 1
  for (int k = 0; k < 32; ++k){
    // ================= P0: ks 0,1 =================
    bf16x8 a0A = *reinterpret_cast<const bf16x8*>(fRd + afo[0]);
    bf16x8 a1A = *reinterpret_cast<const bf16x8*>(fRd + afo[1]);
    bf16x8 b0A = *reinterpret_cast<const bf16x8*>(aRd + bqo[0]);
    bf16x8 b1A = *reinterpret_cast<const bf16x8*>(aRd + bqo[1]);
    bf16x8 a0B = *reinterpret_cast<const bf16x8*>(fRd + (afo[0] ^ 32u));
    bf16x8 a1B = *reinterpret_cast<const bf16x8*>(fRd + (afo[1] ^ 32u));
    bf16x8 b0B = *reinterpret_cast<const bf16x8*>(aRd + (bqo[0] ^ 32u));
    bf16x8 b1B = *reinterpret_cast<const bf16x8*>(aRd + (bqo[1] ^ 32u));
    stage_fs(fWr, fpp); fpp += 128;          // all 4 DMA for chunk k+1
    dgen2(vb, aWr, 0);                       // a(k+1) frags 0,1
    asm volatile("s_waitcnt lgkmcnt(0)" ::: "memory");
    __builtin_amdgcn_sched_barrier(0);
    __builtin_amdgcn_s_barrier();
    __builtin_amdgcn_sched_barrier(0);
    __builtin_amdgcn_s_setprio(1);
    acc00 = __builtin_amdgcn_mfma_f32_32x32x16_bf16(a0A, b0A, acc00, 0, 0, 0);
    acc01 = __builtin_amdgcn_mfma_f32_32x32x16_bf16(a0A, b1A, acc01, 0, 0, 0);
    acc10 = __builtin_amdgcn_mfma_f32_32x32x16_bf16(a1A, b0A, acc10, 0, 0, 0);
    acc11 = __builtin_amdgcn_mfma_f32_32x32x16_bf16(a1A, b1A, acc11, 0, 0, 0);
    acc00 = __builtin_amdgcn_mfma_f32_32x32x16_bf16(a0B, b0B, acc00, 0, 0, 0);
    acc01 = __builtin_amdgcn_mfma_f32_32x32x16_bf16(a0B, b1B, acc01, 0, 0, 0);
    acc10 = __builtin_amdgcn_mfma_f32_32x32x16_bf16(a1B, b0B, acc10, 0, 0, 0);
    acc11 = __builtin_amdgcn_mfma_f32_32x32x16_bf16(a1B, b1B, acc11, 0, 0, 0);
    __builtin_amdgcn_s_setprio(0);
    __builtin_amdgcn_sched_barrier(0);
    __builtin_amdgcn_s_barrier();
    __builtin_amdgcn_sched_barrier(0);
    // ================= P1: ks 2,3 =================
    a0A = *reinterpret_cast<const bf16x8*>(fRd + (afo[0] ^ 64u));
    a1A = *reinterpret_cast<const bf16x8*>(fRd + (afo[1] ^ 64u));
    b0A = *reinterpret_cast<const bf16x8*>(aRd + (bqo[0] ^ 64u));
    b1A = *reinterpret_cast<const bf16x8*>(aRd + (bqo[1] ^ 64u));
    a0B = *reinterpret_cast<const bf16x8*>(fRd + (afo[0] ^ 96u));
    a1B = *reinterpret_cast<const bf16x8*>(fRd + (afo[1] ^ 96u));
    b0B = *reinterpret_cast<const bf16x8*>(aRd + (bqo[0] ^ 96u));
    b1B = *reinterpret_cast<const bf16x8*>(aRd + (bqo[1] ^ 96u));
    dgen2(vb, aWr, 2);                       // a(k+1) frags 2,3
    uint4 vnew = *reinterpret_cast<const uint4*>(vp); vp += 4096;  // v chunk k+2
    // vmcnt(1): only vnew newer than the 4 P0 DMAs -> they are retired here.
    asm volatile("s_waitcnt vmcnt(1) lgkmcnt(0)" ::: "memory");
    __builtin_amdgcn_sched_barrier(0);
    __builtin_amdgcn_s_barrier();
    __builtin_amdgcn_sched_barrier(0);
    __builtin_amdgcn_s_setprio(1);
    acc00 = __builtin_amdgcn_mfma_f32_32x32x16_bf16(a0A, b0A, acc00, 0, 0, 0);
    acc01 = __builtin_amdgcn_mfma_f32_32x32x16_bf16(a0A, b1A, acc01, 0, 0, 0);
    acc10 = __builtin_amdgcn_mfma_f32_32x32x16_bf16(a1A, b0A, acc10, 0, 0, 0);
    acc11 = __builtin_amdgcn_mfma_f32_32x32x16_bf16(a1A, b1A, acc11, 0, 0, 0);
    acc00 = __builtin_amdgcn_mfma_f32_32x32x16_bf16(a0B, b0B, acc00, 0, 0, 0);
    acc01 = __builtin_amdgcn_mfma_f32_32x32x16_bf16(a0B, b1B, acc01, 0, 0, 0);
    acc10 = __builtin_amdgcn_mfma_f32_32x32x16_bf16(a1B, b0B, acc10, 0, 0, 0);
    acc11 = __builtin_amdgcn_mfma_f32_32x32x16_bf16(a1B, b1B, acc11, 0, 0, 0);
    __builtin_amdgcn_s_setprio(0);
    __builtin_amdgcn_sched_barrier(0);
    __builtin_amdgcn_s_barrier();
    __builtin_amdgcn_sched_barrier(0);
    vb = vnew;
    char* tf = fRd; fRd = fWr; fWr = tf;
    char* ta = aRd; aRd = aWr; aWr = ta;
  }

  // ---- store: 32x32 C-layout: col(=q)=lane&31, row(=c)=(reg&3)+8*(reg>>2)+4*(lane>>5)
  const int qcol = q0 + qblk * 64 + lr32;
  #pragma unroll
  for (int r = 0; r < 16; ++r){
    int cr = (r & 3) + 8 * (r >> 2) + 4 * g2;
    out[(cblk * 64 + cr) * HW_SZ + qcol] = acc00[r];
    out[(cblk * 64 + cr) * HW_SZ + qcol + 32] = acc01[r];
    out[(cblk * 64 + 32 + cr) * HW_SZ + qcol] = acc10[r];
    out[(cblk * 64 + 32 + cr) * HW_SZ + qcol + 32] = acc11[r];
  }
}

// ---------- l2norm(channels) of (part0+part1) + residual + relu (in-place into part0)
// + stage-2 conv. h = hat+pt cached in LDS as bf16 (single global read of hat/pt).
__global__ void k_norm(float* __restrict__ hat1, float* __restrict__ hat2,
                       const float* __restrict__ pt1, const float* __restrict__ pt2,
                       const float* __restrict__ f1, const float* __restrict__ f2,
                       const float* __restrict__ cw1, const float* __restrict__ cw2,
                       const float* __restrict__ cb1, const float* __restrict__ cb2,
                       float* __restrict__ cv2){
  const int i = blockIdx.z, n = blockIdx.y, t = threadIdx.x;
  const int ql = t & 63, cg = t >> 6;
  const int q = blockIdx.x * 64 + ql;
  float* hat = (i ? hat2 : hat1) + n * C_CH * HW_SZ;
  const float* pt = (i ? pt2 : pt1) + n * C_CH * HW_SZ;
  const float* f = (i ? f2 : f1) + n * C_CH * HW_SZ;
  __shared__ float ws[C_CH];
  __shared__ float red[4][72];
  __shared__ float invs[64];
  __shared__ unsigned short hLs[C_CH][66];   // bf16 h cache, pad 66
  ws[t] = (i ? cw2 : cw1)[t];
  __syncthreads();
  float s = 0.f;
  #pragma unroll 8
  for (int c = cg * 64; c < cg * 64 + 64; ++c){
    float h = hat[c * HW_SZ + q] + pt[c * HW_SZ + q];
    hLs[c][ql] = f2bf(h);
    s += h * h;
  }
  red[cg][ql] = s; __syncthreads();
  if (t < 64){
    float ss = red[0][t] + red[1][t] + red[2][t] + red[3][t];
    invs[t] = 1.0f / fmaxf(sqrtf(ss), 1e-12f);
  }
  __syncthreads();
  const float inv = invs[ql];
  float ca = 0.f;
  #pragma unroll 8
  for (int c = cg * 64; c < cg * 64 + 64; ++c){
    float vv = fmaxf(bf2f(hLs[c][ql]) * inv + f[c * HW_SZ + q], 0.0f);
    hat[c * HW_SZ + q] = vv;  // in-place fp32: only this thread touches [c][q]
    ca += ws[c] * vv;
  }
  red[cg][ql] = ca; __syncthreads();
  if (t < 64){
    float ss = red[0][t] + red[1][t] + red[2][t] + red[3][t] + (i ? cb2[0] : cb1[0]);
    cv2[(i * 2 + n) * HW_SZ + blockIdx.x * 64 + t] = ss;
  }
}

// ---------- final: out_i = softmax(cv2)_i * fp_i (softmax folded in)
__global__ void k_final(const float* __restrict__ fp1, const float* __restrict__ fp2,
                        const float* __restrict__ cv2, float* __restrict__ outp){
  const int i = blockIdx.z, t = threadIdx.x;
  const int idx4 = (blockIdx.x * 256 + t) * 4;
  const int n = idx4 >> 20;
  const int q = idx4 & (HW_SZ - 1);
  const float* cvrow = cv2 + (i * 2 + n) * HW_SZ;
  __shared__ float red[256];
  float sv[16];
  float m = -1e30f;
  #pragma unroll
  for (int j = 0; j < 16; j++){ sv[j] = cvrow[j * 256 + t]; m = fmaxf(m, sv[j]); }
  red[t] = m; __syncthreads();
  for (int s = 128; s > 0; s >>= 1){ if (t < s) red[t] = fmaxf(red[t], red[t + s]); __syncthreads(); }
  m = red[0]; __syncthreads();
  float sum = 0.f;
  #pragma unroll
  for (int j = 0; j < 16; j++) sum += __expf(sv[j] - m);
  red[t] = sum; __syncthreads();
  for (int s = 128; s > 0; s >>= 1){ if (t < s) red[t] += red[t + s]; __syncthreads(); }
  const float invS = 1.0f / red[0];

  const float* fp = i ? fp2 : fp1;
  float4 vv = *reinterpret_cast<const float4*>(&fp[idx4]);
  float4 o;
  o.x = vv.x * (__expf(cvrow[q + 0] - m) * invS);
  o.y = vv.y * (__expf(cvrow[q + 1] - m) * invS);
  o.z = vv.z * (__expf(cvrow[q + 2] - m) * invS);
  o.w = vv.w * (__expf(cvrow[q + 3] - m) * invS);
  *reinterpret_cast<float4*>(&outp[i * (C_CH * HW_SZ * N_B) + idx4]) = o;
}

extern "C" void kernel_launch(void* const* d_in, const int* in_sizes, int n_in,
                              void* d_out, int out_size, void* d_ws, size_t ws_size,
                              hipStream_t stream){
  const float* f1  = (const float*)d_in[0];
  const float* f2  = (const float*)d_in[1];
  const float* pw1 = (const float*)d_in[2];
  const float* pb1 = (const float*)d_in[3];
  const float* pw2 = (const float*)d_in[4];
  const float* pb2 = (const float*)d_in[5];
  const float* cw1 = (const float*)d_in[6];
  const float* cb1 = (const float*)d_in[7];
  const float* cw2 = (const float*)d_in[8];
  const float* cb2 = (const float*)d_in[9];
  float* ws = (float*)d_ws;
  // layout (float offsets): HAT = part0 (doubles as FP), PT = part1
  float* HAT1 = ws;                                        // 2,097,152 floats each
  float* HAT2 = ws + 2097152;
  float* PT1  = ws + 4194304;
  float* PT2  = ws + 6291456;
  unsigned short* FS1 = (unsigned short*)(ws + 8388608);   // bf16 [C][HW] per n
  unsigned short* FS2 = (unsigned short*)(ws + 9437184);
  unsigned short* CLT1 = (unsigned short*)(ws + 10485760); // bf16 [HW][32] per n
  unsigned short* CLT2 = (unsigned short*)(ws + 10616832);
  float* CV1  = ws + 10747904;
  float* CV2  = ws + 10764288;                             // end 10,780,672 floats ~= 43.1 MiB
  float* outp = (float*)d_out;

  k_conv1   <<<dim3(64, 2, 2), 256, 0, stream>>>(f1, f2, cw1, cw2, cb1, cb2, CV1);
  k_scale_cl<<<dim3(64, 2, 2), 256, 0, stream>>>(f1, f2, CV1, pw1, pw2, pb1, pb2,
                                                 FS1, FS2, CLT1, CLT2);
  k_hat     <<<256, 512, 0, stream>>>(FS1, FS2, CLT1, CLT2, HAT1, HAT2, PT1, PT2);
  k_norm    <<<dim3(64, 2, 2), 256, 0, stream>>>(HAT1, HAT2, PT1, PT2, f1, f2,
                                                 cw1, cw2, cb1, cb2, CV2);
  k_final   <<<dim3(2048, 1, 2), 256, 0, stream>>>(HAT1, HAT2, CV2, outp);
}

// Round 18
// 95.855 us; speedup vs baseline: 1.1673x; 1.1673x over previous
//
#include <hip/hip_runtime.h>
#include <hip/hip_bf16.h>
#include <math.h>

#define N_B 2
#define C_CH 256
#define HW_SZ 4096
#define CL_CH 16

typedef __bf16 bf16x8 __attribute__((ext_vector_type(8)));
typedef float f32x4 __attribute__((ext_vector_type(4)));
typedef float f32x16 __attribute__((ext_vector_type(16)));

__device__ __forceinline__ unsigned short f2bf(float x){
  __hip_bfloat16 b = __float2bfloat16(x);   // RTNE
  return *reinterpret_cast<unsigned short*>(&b);
}
__device__ __forceinline__ float bf2f(unsigned short u){
  unsigned int w = ((unsigned int)u) << 16;
  return *reinterpret_cast<float*>(&w);
}
// packed f32x2 -> bf16x2 (single v_cvt_pk_bf16_f32)
__device__ __forceinline__ unsigned int cvtpk(float a, float b){
  unsigned int r;
  asm("v_cvt_pk_bf16_f32 %0, %1, %2" : "=v"(r) : "v"(a), "v"(b));
  return r;
}
// tanh = 1 - 2*rcp(1+e^{2x}); NaN-safe at +-inf; rcp err ~1e-7 (<< bf16 ulp)
__device__ __forceinline__ float tanh_fast(float x){
  float e = __expf(2.0f * x);
  return fmaf(-2.0f, __builtin_amdgcn_rcpf(1.0f + e), 1.0f);
}
// async global->LDS, 16B per lane; dst must be wave-uniform base (+lane*16 implicit)
__device__ __forceinline__ void gload16(const void* gsrc, void* lds_dst){
  __builtin_amdgcn_global_load_lds(
      (const __attribute__((address_space(1))) unsigned int*)gsrc,
      (__attribute__((address_space(3))) unsigned int*)lds_dst, 16, 0, 0);
}

// ---------- Stage-1 conv (C->1)
__global__ void k_conv1(const float* __restrict__ f1, const float* __restrict__ f2,
                        const float* __restrict__ w1, const float* __restrict__ w2,
                        const float* __restrict__ b1, const float* __restrict__ b2,
                        float* __restrict__ cv){
  const int i = blockIdx.z, n = blockIdx.y, t = threadIdx.x;
  const int ql = t & 63, cg = t >> 6;
  const int q = blockIdx.x * 64 + ql;
  const float* f = (i ? f2 : f1) + n * C_CH * HW_SZ;
  const float* w = i ? w2 : w1;
  __shared__ float ws[C_CH];
  __shared__ float red[4][72];
  ws[t] = w[t];
  __syncthreads();
  float acc = 0.f;
  #pragma unroll 8
  for (int c = cg * 64; c < cg * 64 + 64; ++c)
    acc += f[c * HW_SZ + q] * ws[c];
  red[cg][ql] = acc;
  __syncthreads();
  if (t < 64){
    float s = red[0][t] + red[1][t] + red[2][t] + red[3][t] + (i ? b2[0] : b1[0]);
    cv[(i * 2 + n) * HW_SZ + blockIdx.x * 64 + t] = s;
  }
}

// ---------- fs_i = bf16(pr_i * f_i) ; clT_i[q][0..15] = bf16(pw_i @ (pr*f) + pb_i)
// pr computed INLINE from cv (softmax folded in).
__global__ void k_scale_cl(const float* __restrict__ f1, const float* __restrict__ f2,
                           const float* __restrict__ cv,
                           const float* __restrict__ pw1, const float* __restrict__ pw2,
                           const float* __restrict__ pb1, const float* __restrict__ pb2,
                           unsigned short* __restrict__ fs1, unsigned short* __restrict__ fs2,
                           unsigned short* __restrict__ clT1, unsigned short* __restrict__ clT2){
  const int i = blockIdx.z, n = blockIdx.y, t = threadIdx.x;
  const int ql = t & 63, cg = t >> 6;
  const int q = blockIdx.x * 64 + ql;
  const float* f = (i ? f2 : f1) + n * C_CH * HW_SZ;
  unsigned short* fs = (i ? fs2 : fs1) + n * C_CH * HW_SZ;
  unsigned short* clT = (i ? clT2 : clT1) + n * 32 * HW_SZ;
  const float* pw = i ? pw2 : pw1;
  const float* pb = i ? pb2 : pb1;
  const float* cvrow = cv + (i * 2 + n) * HW_SZ;
  __shared__ float wls[CL_CH * C_CH];
  __shared__ float red[4][CL_CH][66];
  __shared__ float smr[256];
  #pragma unroll
  for (int j = 0; j < 16; j++) wls[j * 256 + t] = pw[j * 256 + t];
  // inline softmax over the 4096-row
  float sv[16];
  float m = -1e30f;
  #pragma unroll
  for (int j = 0; j < 16; j++){ sv[j] = cvrow[j * 256 + t]; m = fmaxf(m, sv[j]); }
  smr[t] = m; __syncthreads();
  for (int s = 128; s > 0; s >>= 1){ if (t < s) smr[t] = fmaxf(smr[t], smr[t + s]); __syncthreads(); }
  m = smr[0]; __syncthreads();
  float sum = 0.f;
  #pragma unroll
  for (int j = 0; j < 16; j++) sum += __expf(sv[j] - m);
  smr[t] = sum; __syncthreads();
  for (int s = 128; s > 0; s >>= 1){ if (t < s) smr[t] += smr[t + s]; __syncthreads(); }
  const float p = __expf(cvrow[q] - m) * (1.0f / smr[0]);

  float acc[16];
  #pragma unroll
  for (int k = 0; k < 16; k++) acc[k] = 0.f;
  for (int c = cg * 64; c < cg * 64 + 64; ++c){
    float vv = f[c * HW_SZ + q] * p;
    fs[c * HW_SZ + q] = f2bf(vv);
    #pragma unroll
    for (int k = 0; k < 16; k++) acc[k] += wls[k * 256 + c] * vv;
  }
  #pragma unroll
  for (int k = 0; k < 16; k++) red[cg][k][ql] = acc[k];
  __syncthreads();
  #pragma unroll
  for (int j = 0; j < 4; j++){
    int e = j * 256 + t; int k = e >> 6, qq = e & 63;
    float s = red[0][k][qq] + red[1][k][qq] + red[2][k][qq] + red[3][k][qq] + pb[k];
    clT[(blockIdx.x * 64 + qq) * 32 + k] = f2bf(s);
  }
  // zero the k in [16,32) pad
  if (t < 128){
    uint4 zv = {0u, 0u, 0u, 0u};
    int qq = t >> 1, half = t & 1;
    *reinterpret_cast<uint4*>(&clT[(blockIdx.x * 64 + qq) * 32 + 16 + half * 8]) = zv;
  }
}

// ---------- fused hat GEMM via MFMA. C=256 x Q=128 tile, split-K over p-halves.
// ONE barrier per chunk: triple-buffered fsA/aT ring (writer (k+2)%3 never
// collides with reader k%3 at <=1-body skew), counted-vmcnt DMA (in flight
// across the barrier), v in registers, setprio around mmain.
__global__ __launch_bounds__(512, 2) void k_hat(
    const unsigned short* __restrict__ fs1, const unsigned short* __restrict__ fs2,
    const unsigned short* __restrict__ clT1, const unsigned short* __restrict__ clT2,
    float* __restrict__ hat1, float* __restrict__ hat2,
    float* __restrict__ pt1, float* __restrict__ pt2){
  const int t = threadIdx.x;
  const int bid = blockIdx.x;
  const int xcd = bid & 7, slot = bid >> 3;  // slot 0..31
  const int z = xcd >> 1;                    // 0..3 -> (n,i); 2 XCDs per (n,i)
  const int n = z & 1, i = z >> 1;
  const int x = slot * 2 + (xcd & 1);        // 0..63
  const int qt = x >> 1, ph = x & 1;         // 32 q-tiles(128) x 2 p-halves
  const int q0 = qt * 128;
  const int pbase = ph * 2048;

  const unsigned short* fs = (i ? fs2 : fs1) + n * C_CH * HW_SZ;
  const unsigned short* uT = (i ? clT1 : clT2) + n * 32 * HW_SZ;  // q-side [HW][32]
  const unsigned short* vT = (i ? clT2 : clT1) + n * 32 * HW_SZ;  // p-side [HW][32]
  float* out = (ph ? (i ? pt2 : pt1) : (i ? hat2 : hat1)) + n * C_CH * HW_SZ;

  __shared__ __align__(16) unsigned short fsA[3][C_CH * 64];  // 32KB each: [c][p swz]
  __shared__ __align__(16) unsigned short aT[3][128 * 64];    // 16KB each: [q][p swz]

  const int wv = t >> 6, l = t & 63;
  const int g4 = l >> 4, lr16 = l & 15;      // d-gen (16x16)
  const int g2 = l >> 5, lr32 = l & 31;      // main (32x32)

  const int pfw = wv & 3;                    // dgen p-frag
  const int qh  = wv >> 2;                   // dgen q-half (4 q-frags each)
  const int cblk = wv & 3, qblk = wv >> 2;   // mmain: c [cblk*64,+64), q [qblk*64,+64)

  // ---- one-time u fragments (k-pad zeroed at source): 4 q-frags per wave
  bf16x8 ub[4];
  #pragma unroll
  for (int j = 0; j < 4; ++j)
    ub[j] = *reinterpret_cast<const bf16x8*>(&uT[(q0 + qh * 64 + j * 16 + lr16) * 32 + g4 * 8]);

  f32x16 acc00, acc01, acc10, acc11;         // [cf][qf]
  #pragma unroll
  for (int r = 0; r < 16; ++r){ acc00[r] = 0.f; acc01[r] = 0.f; acc10[r] = 0.f; acc11[r] = 0.f; }
  const f32x4 zz = {0.f, 0.f, 0.f, 0.f};

  // ---- per-thread byte offsets (computed once); slot swizzle:
  // slot(row, u) = u ^ (row&7) ^ ((row>>3)&1)<<2 ^ ((row>>4)&1)<<1
  int fs_src[4];
  #pragma unroll
  for (int it = 0; it < 4; ++it){
    int d = it * 512 + t; int c = d >> 3, sl = d & 7;
    int u = sl ^ (c & 7) ^ (((c >> 3) & 1) << 2) ^ (((c >> 4) & 1) << 1);
    fs_src[it] = c * (HW_SZ * 2) + u * 16;
  }
  const int vgo = (pfw * 16 + lr16) * 64 + g4 * 16;  // per-lane byte off within v chunk
  unsigned atw0;
  {
    int qd = qh * 64 + lr16;   // bit4 of qd = 0; j-walk adds j*16 (bit4 = j&1)
    int sw = (pfw * 2 + (g4 >> 1)) ^ (qd & 7) ^ (((qd >> 3) & 1) << 2);
    atw0 = qd * 128 + sw * 16 + (g4 & 1) * 8;
  }
  unsigned afo[2], bqo[2];
  #pragma unroll
  for (int cf = 0; cf < 2; ++cf){
    int crow = cblk * 64 + cf * 32 + lr32;
    afo[cf] = crow * 128 +
      ((g2 ^ (crow & 7) ^ (((crow >> 3) & 1) << 2) ^ (((crow >> 4) & 1) << 1)) << 4);
  }
  #pragma unroll
  for (int qf = 0; qf < 2; ++qf){
    int qrow = qblk * 64 + qf * 32 + lr32;
    bqo[qf] = qrow * 128 +
      ((g2 ^ (qrow & 7) ^ (((qrow >> 3) & 1) << 2) ^ (((qrow >> 4) & 1) << 1)) << 4);
  }

  auto stage_fs = [&](char* dstbase, const char* src){
    #pragma unroll
    for (int it = 0; it < 4; ++it)
      gload16(src + fs_src[it], dstbase + (it * 512 + wv * 64) * 16);
  };
  auto dgen = [&](uint4 vr, char* atB){
    bf16x8 av = *reinterpret_cast<bf16x8*>(&vr);
    #pragma unroll
    for (int j = 0; j < 4; ++j){
      f32x4 d = __builtin_amdgcn_mfma_f32_16x16x32_bf16(av, ub[j], zz, 0, 0, 0);
      uint2 pk;
      pk.x = cvtpk(tanh_fast(d[0]), tanh_fast(d[1]));
      pk.y = cvtpk(tanh_fast(d[2]), tanh_fast(d[3]));
      unsigned off = (atw0 + (unsigned)(j * 2048)) ^ ((unsigned)(j & 1) << 5);
      *reinterpret_cast<uint2*>(atB + off) = pk;
    }
  };
  auto mmain = [&](const char* faB, const char* atB){
    __builtin_amdgcn_s_setprio(1);
    #pragma unroll
    for (int ks = 0; ks < 4; ++ks){
      unsigned kx = (unsigned)(ks << 5);
      bf16x8 a0 = *reinterpret_cast<const bf16x8*>(faB + (afo[0] ^ kx));
      bf16x8 a1 = *reinterpret_cast<const bf16x8*>(faB + (afo[1] ^ kx));
      bf16x8 b0 = *reinterpret_cast<const bf16x8*>(atB + (bqo[0] ^ kx));
      bf16x8 b1 = *reinterpret_cast<const bf16x8*>(atB + (bqo[1] ^ kx));
      acc00 = __builtin_amdgcn_mfma_f32_32x32x16_bf16(a0, b0, acc00, 0, 0, 0);
      acc01 = __builtin_amdgcn_mfma_f32_32x32x16_bf16(a0, b1, acc01, 0, 0, 0);
      acc10 = __builtin_amdgcn_mfma_f32_32x32x16_bf16(a1, b0, acc10, 0, 0, 0);
      acc11 = __builtin_amdgcn_mfma_f32_32x32x16_bf16(a1, b1, acc11, 0, 0, 0);
    }
    __builtin_amdgcn_s_setprio(0);
  };

  // advancing pointers (hot loop: one add each)
  const char* fpp = (const char*)fs + pbase * 2;       // fs chunk base, +128B/chunk
  const char* vp  = (const char*)vT + pbase * 64 + vgo;// per-lane v ptr, +4096B/chunk

  // rotating LDS role pointers (named vars -> register moves, no scratch)
  char *fRd = (char*)&fsA[0][0], *fWr = (char*)&fsA[1][0], *fSp = (char*)&fsA[2][0];
  char *aRd = (char*)&aT[0][0],  *aWr = (char*)&aT[1][0],  *aSp = (char*)&aT[2][0];

  // ---- prologue: DMA chunk0 FIRST, then vloads (vload retirement implies DMA done)
  stage_fs(fRd, fpp); fpp += 128;
  uint4 vb;
  {
    uint4 va = *reinterpret_cast<const uint4*>(vp);        // v chunk 0
    vb = *reinterpret_cast<const uint4*>(vp + 4096);       // v chunk 1
    vp += 8192;
    dgen(va, aRd);  // waits v(0) (counted vmcnt) => chunk-0 DMA retired per-wave
  }

  // ---- main loop: 32 chunks, ONE drain-free barrier each.
  // Body k: {DMA(k+1)->fWr, load v(k+2), dgen(k+1)->aWr [waits v(k+1) =>
  // DMA(k) retired this wave], lgkmcnt(0), barrier [globalizes: all DMA(k)
  // + all aT(k) writes visible], mmain(k) on fRd/aRd, rotate}.
  // Max skew 1 body; writer index differs from any live reader (mod 3).
  // Tail overreads (fs chunk 32, v chunk 33, garbage dgen->aSp never read)
  // land in allocated ws regions.
  #pragma unroll 1
  for (int k = 0; k < 32; ++k){
    stage_fs(fWr, fpp); fpp += 128;                        // DMA chunk k+1
    uint4 vnew = *reinterpret_cast<const uint4*>(vp); vp += 4096;  // v chunk k+2
    dgen(vb, aWr);                                         // a(k+1)
    vb = vnew;
    asm volatile("s_waitcnt lgkmcnt(0)" ::: "memory");
    __builtin_amdgcn_sched_barrier(0);
    __builtin_amdgcn_s_barrier();
    __builtin_amdgcn_sched_barrier(0);
    mmain(fRd, aRd);
    char* tf = fRd; fRd = fWr; fWr = fSp; fSp = tf;
    char* ta = aRd; aRd = aWr; aWr = aSp; aSp = ta;
  }

  // ---- store: 32x32 C-layout: col(=q)=lane&31, row(=c)=(reg&3)+8*(reg>>2)+4*(lane>>5)
  const int qcol = q0 + qblk * 64 + lr32;
  #pragma unroll
  for (int r = 0; r < 16; ++r){
    int cr = (r & 3) + 8 * (r >> 2) + 4 * g2;
    out[(cblk * 64 + cr) * HW_SZ + qcol] = acc00[r];
    out[(cblk * 64 + cr) * HW_SZ + qcol + 32] = acc01[r];
    out[(cblk * 64 + 32 + cr) * HW_SZ + qcol] = acc10[r];
    out[(cblk * 64 + 32 + cr) * HW_SZ + qcol + 32] = acc11[r];
  }
}

// ---------- l2norm(channels) of (part0+part1) + residual + relu (in-place into part0)
// + stage-2 conv. h = hat+pt cached in LDS as bf16 (single global read of hat/pt).
__global__ void k_norm(float* __restrict__ hat1, float* __restrict__ hat2,
                       const float* __restrict__ pt1, const float* __restrict__ pt2,
                       const float* __restrict__ f1, const float* __restrict__ f2,
                       const float* __restrict__ cw1, const float* __restrict__ cw2,
                       const float* __restrict__ cb1, const float* __restrict__ cb2,
                       float* __restrict__ cv2){
  const int i = blockIdx.z, n = blockIdx.y, t = threadIdx.x;
  const int ql = t & 63, cg = t >> 6;
  const int q = blockIdx.x * 64 + ql;
  float* hat = (i ? hat2 : hat1) + n * C_CH * HW_SZ;
  const float* pt = (i ? pt2 : pt1) + n * C_CH * HW_SZ;
  const float* f = (i ? f2 : f1) + n * C_CH * HW_SZ;
  __shared__ float ws[C_CH];
  __shared__ float red[4][72];
  __shared__ float invs[64];
  __shared__ unsigned short hLs[C_CH][66];   // bf16 h cache, pad 66
  ws[t] = (i ? cw2 : cw1)[t];
  __syncthreads();
  float s = 0.f;
  #pragma unroll 8
  for (int c = cg * 64; c < cg * 64 + 64; ++c){
    float h = hat[c * HW_SZ + q] + pt[c * HW_SZ + q];
    hLs[c][ql] = f2bf(h);
    s += h * h;
  }
  red[cg][ql] = s; __syncthreads();
  if (t < 64){
    float ss = red[0][t] + red[1][t] + red[2][t] + red[3][t];
    invs[t] = 1.0f / fmaxf(sqrtf(ss), 1e-12f);
  }
  __syncthreads();
  const float inv = invs[ql];
  float ca = 0.f;
  #pragma unroll 8
  for (int c = cg * 64; c < cg * 64 + 64; ++c){
    float vv = fmaxf(bf2f(hLs[c][ql]) * inv + f[c * HW_SZ + q], 0.0f);
    hat[c * HW_SZ + q] = vv;  // in-place fp32: only this thread touches [c][q]
    ca += ws[c] * vv;
  }
  red[cg][ql] = ca; __syncthreads();
  if (t < 64){
    float ss = red[0][t] + red[1][t] + red[2][t] + red[3][t] + (i ? cb2[0] : cb1[0]);
    cv2[(i * 2 + n) * HW_SZ + blockIdx.x * 64 + t] = ss;
  }
}

// ---------- final: out_i = softmax(cv2)_i * fp_i (softmax folded in)
__global__ void k_final(const float* __restrict__ fp1, const float* __restrict__ fp2,
                        const float* __restrict__ cv2, float* __restrict__ outp){
  const int i = blockIdx.z, t = threadIdx.x;
  const int idx4 = (blockIdx.x * 256 + t) * 4;
  const int n = idx4 >> 20;
  const int q = idx4 & (HW_SZ - 1);
  const float* cvrow = cv2 + (i * 2 + n) * HW_SZ;
  __shared__ float red[256];
  float sv[16];
  float m = -1e30f;
  #pragma unroll
  for (int j = 0; j < 16; j++){ sv[j] = cvrow[j * 256 + t]; m = fmaxf(m, sv[j]); }
  red[t] = m; __syncthreads();
  for (int s = 128; s > 0; s >>= 1){ if (t < s) red[t] = fmaxf(red[t], red[t + s]); __syncthreads(); }
  m = red[0]; __syncthreads();
  float sum = 0.f;
  #pragma unroll
  for (int j = 0; j < 16; j++) sum += __expf(sv[j] - m);
  red[t] = sum; __syncthreads();
  for (int s = 128; s > 0; s >>= 1){ if (t < s) red[t] += red[t + s]; __syncthreads(); }
  const float invS = 1.0f / red[0];

  const float* fp = i ? fp2 : fp1;
  float4 vv = *reinterpret_cast<const float4*>(&fp[idx4]);
  float4 o;
  o.x = vv.x * (__expf(cvrow[q + 0] - m) * invS);
  o.y = vv.y * (__expf(cvrow[q + 1] - m) * invS);
  o.z = vv.z * (__expf(cvrow[q + 2] - m) * invS);
  o.w = vv.w * (__expf(cvrow[q + 3] - m) * invS);
  *reinterpret_cast<float4*>(&outp[i * (C_CH * HW_SZ * N_B) + idx4]) = o;
}

extern "C" void kernel_launch(void* const* d_in, const int* in_sizes, int n_in,
                              void* d_out, int out_size, void* d_ws, size_t ws_size,
                              hipStream_t stream){
  const float* f1  = (const float*)d_in[0];
  const float* f2  = (const float*)d_in[1];
  const float* pw1 = (const float*)d_in[2];
  const float* pb1 = (const float*)d_in[3];
  const float* pw2 = (const float*)d_in[4];
  const float* pb2 = (const float*)d_in[5];
  const float* cw1 = (const float*)d_in[6];
  const float* cb1 = (const float*)d_in[7];
  const float* cw2 = (const float*)d_in[8];
  const float* cb2 = (const float*)d_in[9];
  float* ws = (float*)d_ws;
  // layout (float offsets): HAT = part0 (doubles as FP), PT = part1
  float* HAT1 = ws;                                        // 2,097,152 floats each
  float* HAT2 = ws + 2097152;
  float* PT1  = ws + 4194304;
  float* PT2  = ws + 6291456;
  unsigned short* FS1 = (unsigned short*)(ws + 8388608);   // bf16 [C][HW] per n
  unsigned short* FS2 = (unsigned short*)(ws + 9437184);
  unsigned short* CLT1 = (unsigned short*)(ws + 10485760); // bf16 [HW][32] per n
  unsigned short* CLT2 = (unsigned short*)(ws + 10616832);
  float* CV1  = ws + 10747904;
  float* CV2  = ws + 10764288;                             // end 10,780,672 floats ~= 43.1 MiB
  float* outp = (float*)d_out;

  k_conv1   <<<dim3(64, 2, 2), 256, 0, stream>>>(f1, f2, cw1, cw2, cb1, cb2, CV1);
  k_scale_cl<<<dim3(64, 2, 2), 256, 0, stream>>>(f1, f2, CV1, pw1, pw2, pb1, pb2,
                                                 FS1, FS2, CLT1, CLT2);
  k_hat     <<<256, 512, 0, stream>>>(FS1, FS2, CLT1, CLT2, HAT1, HAT2, PT1, PT2);
  k_norm    <<<dim3(64, 2, 2), 256, 0, stream>>>(HAT1, HAT2, PT1, PT2, f1, f2,
                                                 cw1, cw2, cb1, cb2, CV2);
  k_final   <<<dim3(2048, 1, 2), 256, 0, stream>>>(HAT1, HAT2, CV2, outp);
}